// Round 1
// baseline (150.675 us; speedup 1.0000x reference)
//
#include <hip/hip_runtime.h>
#include <hip/hip_bf16.h>

#define B 4096
#define S 200
#define EMB_DIM 128
#define HIDDEN 256
#define NUM_CLASSES 20

// ---------------------------------------------------------------------------
// Kernel 1: embedding gather + masked mean pool.
// One block per batch row. 256 threads = 8 position-groups x 32 lanes.
// Each lane loads one float4 (16B) of the 128-float embedding row -> the
// 32 lanes of a group cover one row with fully-coalesced 512B.
// Groups stride over positions s = g, g+8, ... < L, then LDS tree-reduce.
// ---------------------------------------------------------------------------
__global__ __launch_bounds__(256) void pool_kernel(
    const int* __restrict__ x,        // [B, S]
    const int* __restrict__ lens,     // [B]
    const float* __restrict__ emb,    // [VOCAB, EMB_DIM]
    float* __restrict__ pooled)       // [B, EMB_DIM]
{
    const int b = blockIdx.x;
    const int L = lens[b];
    const int t = threadIdx.x;
    const int g = t >> 5;    // position group 0..7
    const int d = t & 31;    // float4 slot within row (32 * 4 = 128 floats)

    const int* xr = x + (long)b * S;

    float4 acc = make_float4(0.f, 0.f, 0.f, 0.f);
    for (int s = g; s < L; s += 8) {
        const int idx = xr[s];
        const float4 v = ((const float4*)(emb + (long)idx * EMB_DIM))[d];
        acc.x += v.x; acc.y += v.y; acc.z += v.z; acc.w += v.w;
    }

    __shared__ float4 tmp[8][32];
    tmp[g][d] = acc;
    __syncthreads();

    if (t < 32) {
        float4 s0 = tmp[0][t];
        #pragma unroll
        for (int gg = 1; gg < 8; ++gg) {
            const float4 v = tmp[gg][t];
            s0.x += v.x; s0.y += v.y; s0.z += v.z; s0.w += v.w;
        }
        const float inv = 1.0f / (float)L;
        s0.x *= inv; s0.y *= inv; s0.z *= inv; s0.w *= inv;
        ((float4*)(pooled + (long)b * EMB_DIM))[t] = s0;
    }
}

// ---------------------------------------------------------------------------
// Kernel 2: fused 2-layer MLP on pooled features.
// 16 batch rows per block, 256 threads.
// Layer 1: thread j computes hidden unit j for all 16 rows.
//   W1[k*256 + j] reads are coalesced across threads; pooled tile is
//   broadcast from LDS (same address across the wave -> no conflict).
// Layer 2: 16*20 = 320 outputs, distributed over the 256 threads.
// ---------------------------------------------------------------------------
#define TB 16
__global__ __launch_bounds__(256) void mlp_kernel(
    const float* __restrict__ pooled, // [B, EMB_DIM]
    const float* __restrict__ W1,     // [EMB_DIM, HIDDEN]
    const float* __restrict__ b1,     // [HIDDEN]
    const float* __restrict__ W2,     // [HIDDEN, NUM_CLASSES]
    const float* __restrict__ b2,     // [NUM_CLASSES]
    float* __restrict__ out)          // [B, NUM_CLASSES]
{
    __shared__ float P[TB][EMB_DIM];   // 8 KB
    __shared__ float H[TB][HIDDEN];    // 16 KB

    const int t = threadIdx.x;
    const int b0 = blockIdx.x * TB;

    // Stage pooled tile (TB*128 = 2048 floats, 8 per thread, coalesced).
    for (int i = t; i < TB * EMB_DIM; i += 256) {
        P[i >> 7][i & 127] = pooled[(long)b0 * EMB_DIM + i];
    }
    __syncthreads();

    // Layer 1: hidden unit j = t, all TB rows at once.
    float acc[TB];
    #pragma unroll
    for (int r = 0; r < TB; ++r) acc[r] = 0.f;

    for (int k = 0; k < EMB_DIM; ++k) {
        const float w = W1[k * HIDDEN + t];
        #pragma unroll
        for (int r = 0; r < TB; ++r) acc[r] += P[r][k] * w;
    }

    const float bb = b1[t];
    #pragma unroll
    for (int r = 0; r < TB; ++r) H[r][t] = fmaxf(acc[r] + bb, 0.f);
    __syncthreads();

    // Layer 2: 320 outputs over 256 threads.
    for (int o = t; o < TB * NUM_CLASSES; o += 256) {
        const int r = o / NUM_CLASSES;
        const int c = o - r * NUM_CLASSES;
        float a = b2[c];
        for (int k = 0; k < HIDDEN; ++k) {
            a += H[r][k] * W2[k * NUM_CLASSES + c];
        }
        out[(long)(b0 + r) * NUM_CLASSES + c] = a;
    }
}

extern "C" void kernel_launch(void* const* d_in, const int* in_sizes, int n_in,
                              void* d_out, int out_size, void* d_ws, size_t ws_size,
                              hipStream_t stream) {
    const int*   x    = (const int*)d_in[0];
    const int*   lens = (const int*)d_in[1];
    const float* emb  = (const float*)d_in[2];
    const float* W1   = (const float*)d_in[3];
    const float* b1   = (const float*)d_in[4];
    const float* W2   = (const float*)d_in[5];
    const float* b2   = (const float*)d_in[6];
    float*       out  = (float*)d_out;

    float* pooled = (float*)d_ws;   // B * EMB_DIM floats = 2 MB

    pool_kernel<<<B, 256, 0, stream>>>(x, lens, emb, pooled);
    mlp_kernel<<<B / TB, 256, 0, stream>>>(pooled, W1, b1, W2, b2, out);
}

// Round 2
// 135.632 us; speedup vs baseline: 1.1109x; 1.1109x over previous
//
#include <hip/hip_runtime.h>
#include <hip/hip_bf16.h>

#define B 4096
#define S 200
#define SPAD 224          // S rounded up to multiple of 32
#define EMB_DIM 128
#define HIDDEN 256
#define NUM_CLASSES 20

// ---------------------------------------------------------------------------
// Kernel 1: embedding gather + masked mean pool.
// One block per batch row. 256 threads = 8 position-groups x 32 lanes;
// lane d loads float4 #d of the 128-float embedding row (512B coalesced).
//
// vs round 0:
//  - indices staged in LDS first (no dependent global index load in the loop)
//  - gather unrolled 4-deep with independent accumulators (4 outstanding
//    vmem gathers per lane instead of ~1 -> latency hiding)
//  - out-of-range positions gather emb row 0, which is all zeros
//    (padding_idx=0) -> branch-free padded loop, row 0 stays L2-resident
// ---------------------------------------------------------------------------
__global__ __launch_bounds__(256) void pool_kernel(
    const int* __restrict__ x,        // [B, S]
    const int* __restrict__ lens,     // [B]
    const float* __restrict__ emb,    // [VOCAB, EMB_DIM]
    float* __restrict__ pooled)       // [B, EMB_DIM]
{
    const int b = blockIdx.x;
    const int t = threadIdx.x;
    const int L = lens[b];

    __shared__ int sidx[SPAD];        // 896 B
    __shared__ float4 tmp[8][32];     // 4 KB

    // Stage indices; positions >= L map to row 0 (zeros).
    if (t < SPAD) {
        int v = 0;
        if (t < L) v = x[(long)b * S + t];   // L <= S so in-bounds
        sidx[t] = v;
    }
    __syncthreads();

    const int g = t >> 5;    // position group 0..7
    const int d = t & 31;    // float4 slot within row

    float4 a0 = make_float4(0.f, 0.f, 0.f, 0.f);
    float4 a1 = a0, a2 = a0, a3 = a0;

    const int Lpad = (L + 31) & ~31; // multiple of 32, <= SPAD
    for (int base = g; base < Lpad; base += 32) {
        const int i0 = sidx[base];
        const int i1 = sidx[base + 8];
        const int i2 = sidx[base + 16];
        const int i3 = sidx[base + 24];
        const float4 v0 = ((const float4*)(emb + (long)i0 * EMB_DIM))[d];
        const float4 v1 = ((const float4*)(emb + (long)i1 * EMB_DIM))[d];
        const float4 v2 = ((const float4*)(emb + (long)i2 * EMB_DIM))[d];
        const float4 v3 = ((const float4*)(emb + (long)i3 * EMB_DIM))[d];
        a0.x += v0.x; a0.y += v0.y; a0.z += v0.z; a0.w += v0.w;
        a1.x += v1.x; a1.y += v1.y; a1.z += v1.z; a1.w += v1.w;
        a2.x += v2.x; a2.y += v2.y; a2.z += v2.z; a2.w += v2.w;
        a3.x += v3.x; a3.y += v3.y; a3.z += v3.z; a3.w += v3.w;
    }
    a0.x += a1.x + a2.x + a3.x;
    a0.y += a1.y + a2.y + a3.y;
    a0.z += a1.z + a2.z + a3.z;
    a0.w += a1.w + a2.w + a3.w;

    tmp[g][d] = a0;
    __syncthreads();

    if (t < 32) {
        float4 s0 = tmp[0][t];
        #pragma unroll
        for (int gg = 1; gg < 8; ++gg) {
            const float4 v = tmp[gg][t];
            s0.x += v.x; s0.y += v.y; s0.z += v.z; s0.w += v.w;
        }
        const float inv = 1.0f / (float)L;
        s0.x *= inv; s0.y *= inv; s0.z *= inv; s0.w *= inv;
        ((float4*)(pooled + (long)b * EMB_DIM))[t] = s0;
    }
}

// ---------------------------------------------------------------------------
// Kernel 2: fused 2-layer MLP on pooled features.
// TB=8 rows per block -> 512 blocks (2 blocks/CU, 8 waves/CU; round-0 TB=16
// gave only 1 block/CU and exposed the W1 load latency).
// Layer 1: thread j computes hidden unit j for all TB rows; W1 reads
// coalesced across threads; pooled tile broadcast from LDS via float4.
// ---------------------------------------------------------------------------
#define TB 8
__global__ __launch_bounds__(256) void mlp_kernel(
    const float* __restrict__ pooled, // [B, EMB_DIM]
    const float* __restrict__ W1,     // [EMB_DIM, HIDDEN]
    const float* __restrict__ b1,     // [HIDDEN]
    const float* __restrict__ W2,     // [HIDDEN, NUM_CLASSES]
    const float* __restrict__ b2,     // [NUM_CLASSES]
    float* __restrict__ out)          // [B, NUM_CLASSES]
{
    __shared__ float P[TB][EMB_DIM];   // 4 KB
    __shared__ float H[TB][HIDDEN];    // 8 KB

    const int t = threadIdx.x;
    const int b0 = blockIdx.x * TB;

    for (int i = t; i < TB * EMB_DIM; i += 256) {
        P[i >> 7][i & 127] = pooled[(long)b0 * EMB_DIM + i];
    }
    __syncthreads();

    float acc[TB];
    #pragma unroll
    for (int r = 0; r < TB; ++r) acc[r] = 0.f;

    // 4 k-steps per float4 LDS broadcast read.
    for (int k4 = 0; k4 < EMB_DIM; k4 += 4) {
        float4 p[TB];
        #pragma unroll
        for (int r = 0; r < TB; ++r) p[r] = *(const float4*)&P[r][k4];
        #pragma unroll
        for (int kk = 0; kk < 4; ++kk) {
            const float w = W1[(k4 + kk) * HIDDEN + t];
            #pragma unroll
            for (int r = 0; r < TB; ++r) {
                const float pv = (kk == 0) ? p[r].x : (kk == 1) ? p[r].y
                               : (kk == 2) ? p[r].z : p[r].w;
                acc[r] += pv * w;
            }
        }
    }

    const float bb = b1[t];
    #pragma unroll
    for (int r = 0; r < TB; ++r) H[r][t] = fmaxf(acc[r] + bb, 0.f);
    __syncthreads();

    // Layer 2: TB*20 = 160 outputs over 256 threads.
    if (t < TB * NUM_CLASSES) {
        const int r = t / NUM_CLASSES;
        const int c = t - r * NUM_CLASSES;
        float a = b2[c];
        for (int k = 0; k < HIDDEN; ++k) {
            a += H[r][k] * W2[k * NUM_CLASSES + c];
        }
        out[(long)(b0 + r) * NUM_CLASSES + c] = a;
    }
}

extern "C" void kernel_launch(void* const* d_in, const int* in_sizes, int n_in,
                              void* d_out, int out_size, void* d_ws, size_t ws_size,
                              hipStream_t stream) {
    const int*   x    = (const int*)d_in[0];
    const int*   lens = (const int*)d_in[1];
    const float* emb  = (const float*)d_in[2];
    const float* W1   = (const float*)d_in[3];
    const float* b1   = (const float*)d_in[4];
    const float* W2   = (const float*)d_in[5];
    const float* b2   = (const float*)d_in[6];
    float*       out  = (float*)d_out;

    float* pooled = (float*)d_ws;   // B * EMB_DIM floats = 2 MB

    pool_kernel<<<B, 256, 0, stream>>>(x, lens, emb, pooled);
    mlp_kernel<<<B / TB, 256, 0, stream>>>(pooled, W1, b1, W2, b2, out);
}

// Round 3
// 126.517 us; speedup vs baseline: 1.1909x; 1.0720x over previous
//
#include <hip/hip_runtime.h>
#include <hip/hip_bf16.h>

#define B 4096
#define S 200
#define EMB_DIM 128
#define HIDDEN 256
#define NUM_CLASSES 20

// ---------------------------------------------------------------------------
// Fully fused: embedding gather + masked mean pool + 2-layer MLP.
// One block (256 threads) per batch row, 4096 blocks.
//
// Gather phase: 8 position-groups x 32 lanes; lane d loads float4 #d of the
// 512B embedding row. 8-deep unroll (64 positions per round, avg L~100 -> 2
// rounds) with the next round's indices prefetched from LDS before the vmcnt
// wait -> ~8 outstanding gathers/lane, half the dependent rounds of round-2.
// Positions >= L gather emb row 0 which is all zeros (padding_idx=0).
//
// MLP phase: runs on the same block's otherwise-idle VALU slots (round-1
// pool showed VALUBusy 6.5%). W1 (131 KB) streams from L2 per block.
// Removes the separate mlp dispatch + launch gap + pooled round-trip.
// ---------------------------------------------------------------------------
__global__ __launch_bounds__(256, 4) void fused_kernel(
    const int* __restrict__ x,        // [B, S]
    const int* __restrict__ lens,     // [B]
    const float* __restrict__ emb,    // [VOCAB, EMB_DIM]
    const float* __restrict__ W1,     // [EMB_DIM, HIDDEN]
    const float* __restrict__ b1,     // [HIDDEN]
    const float* __restrict__ W2,     // [HIDDEN, NUM_CLASSES]
    const float* __restrict__ b2,     // [NUM_CLASSES]
    float* __restrict__ out)          // [B, NUM_CLASSES]
{
    __shared__ int    sidx[256];              // 1 KB (Lpad <= 256)
    __shared__ float4 tmp[8][32];             // 4 KB
    __shared__ float  P[EMB_DIM];             // 512 B pooled row
    __shared__ float  H[HIDDEN];              // 1 KB hidden row
    __shared__ float  part[8][NUM_CLASSES];   // 640 B layer-2 partials

    const int b = blockIdx.x;
    const int t = threadIdx.x;
    const int L = lens[b];

    // Stage indices; positions >= L map to row 0 (zeros). L <= S = 200 < 256.
    {
        int v = 0;
        if (t < L) v = x[(long)b * S + t];
        sidx[t] = v;
    }
    __syncthreads();

    const int g = t >> 5;    // position group 0..7
    const int d = t & 31;    // float4 slot within row

    const int Lpad  = (L + 63) & ~63;   // 64..256, block-uniform
    const int nIter = Lpad >> 6;        // 1..4

    float4 acc[8];
    #pragma unroll
    for (int j = 0; j < 8; ++j) acc[j] = make_float4(0.f, 0.f, 0.f, 0.f);

    // Position for (iter, group g, slot j) = iter*64 + g + 8*j.
    int cur[8], nxt[8];
    #pragma unroll
    for (int j = 0; j < 8; ++j) cur[j] = sidx[g + 8 * j];

    for (int it = 0; it < nIter; ++it) {
        float4 v[8];
        #pragma unroll
        for (int j = 0; j < 8; ++j)
            v[j] = ((const float4*)(emb + (long)cur[j] * EMB_DIM))[d];

        // Prefetch next round's indices before the accumulate (vmcnt wait).
        const int nb = (it + 1) << 6;
        if (it + 1 < nIter) {
            #pragma unroll
            for (int j = 0; j < 8; ++j) nxt[j] = sidx[nb + g + 8 * j];
        }

        #pragma unroll
        for (int j = 0; j < 8; ++j) {
            acc[j].x += v[j].x; acc[j].y += v[j].y;
            acc[j].z += v[j].z; acc[j].w += v[j].w;
        }
        #pragma unroll
        for (int j = 0; j < 8; ++j) cur[j] = nxt[j];
    }

    // Intra-lane then cross-group reduction.
    #pragma unroll
    for (int j = 1; j < 8; ++j) {
        acc[0].x += acc[j].x; acc[0].y += acc[j].y;
        acc[0].z += acc[j].z; acc[0].w += acc[j].w;
    }
    tmp[g][d] = acc[0];
    __syncthreads();

    if (t < 32) {
        float4 s0 = tmp[0][t];
        #pragma unroll
        for (int gg = 1; gg < 8; ++gg) {
            const float4 v = tmp[gg][t];
            s0.x += v.x; s0.y += v.y; s0.z += v.z; s0.w += v.w;
        }
        const float inv = 1.0f / (float)L;
        s0.x *= inv; s0.y *= inv; s0.z *= inv; s0.w *= inv;
        ((float4*)P)[t] = s0;
    }
    __syncthreads();

    // Layer 1: thread t computes hidden unit t. P[k] broadcasts from LDS;
    // W1 reads coalesced (256 B per wave per k). 4 independent partials.
    {
        float h0 = 0.f, h1 = 0.f, h2 = 0.f, h3 = 0.f;
        for (int k = 0; k < EMB_DIM; k += 4) {
            h0 += P[k]     * W1[(k)     * HIDDEN + t];
            h1 += P[k + 1] * W1[(k + 1) * HIDDEN + t];
            h2 += P[k + 2] * W1[(k + 2) * HIDDEN + t];
            h3 += P[k + 3] * W1[(k + 3) * HIDDEN + t];
        }
        H[t] = fmaxf(h0 + h1 + h2 + h3 + b1[t], 0.f);
    }
    __syncthreads();

    // Layer 2: 20 classes x 8 k-segments = 160 threads, 32-FMA chains.
    if (t < 8 * NUM_CLASSES) {
        const int j = t / NUM_CLASSES;        // k-segment 0..7
        const int c = t - j * NUM_CLASSES;    // class 0..19
        const int k0 = j * 32;
        float a = 0.f;
        for (int k = k0; k < k0 + 32; ++k)
            a += H[k] * W2[k * NUM_CLASSES + c];
        part[j][c] = a;
    }
    __syncthreads();

    if (t < NUM_CLASSES) {
        float a = b2[t];
        #pragma unroll
        for (int j = 0; j < 8; ++j) a += part[j][t];
        out[(long)b * NUM_CLASSES + t] = a;
    }
}

extern "C" void kernel_launch(void* const* d_in, const int* in_sizes, int n_in,
                              void* d_out, int out_size, void* d_ws, size_t ws_size,
                              hipStream_t stream) {
    const int*   x    = (const int*)d_in[0];
    const int*   lens = (const int*)d_in[1];
    const float* emb  = (const float*)d_in[2];
    const float* W1   = (const float*)d_in[3];
    const float* b1   = (const float*)d_in[4];
    const float* W2   = (const float*)d_in[5];
    const float* b2   = (const float*)d_in[6];
    float*       out  = (float*)d_out;

    fused_kernel<<<B, 256, 0, stream>>>(x, lens, emb, W1, b1, W2, b2, out);
}

// Round 4
// 125.006 us; speedup vs baseline: 1.2053x; 1.0121x over previous
//
#include <hip/hip_runtime.h>
#include <hip/hip_bf16.h>

#define B 4096
#define S 200
#define EMB_DIM 128
#define HIDDEN 256
#define NUM_CLASSES 20
#define VOCAB 100000
#define RB 2               // batch rows per block

typedef __attribute__((ext_vector_type(8))) unsigned short ushort8;

// RNE float -> bf16 (inputs are finite, no NaN handling needed)
__device__ __forceinline__ unsigned short f2bf(float f) {
    unsigned u = __float_as_uint(f);
    unsigned r = u + 0x7fffu + ((u >> 16) & 1u);
    return (unsigned short)(r >> 16);
}

// ---------------------------------------------------------------------------
// Pass 1: stream-convert the fp32 table (51.2 MB, cold in HBM because the
// harness's 268 MB ws re-poison flushes L3 every iteration) into a 25.6 MB
// bf16 table in d_ws. Sequential HBM reads run at ~6 TB/s vs the ~2 TB/s the
// random 512B gather was getting; the bf16 table it leaves behind is
// L3-resident for pass 2 and halves the gathered bytes.
// ---------------------------------------------------------------------------
__global__ __launch_bounds__(256) void convert_kernel(
    const float* __restrict__ emb,          // [VOCAB*EMB_DIM]
    unsigned short* __restrict__ embh)      // [VOCAB*EMB_DIM] bf16 bits
{
    const long i = ((long)blockIdx.x * 256 + threadIdx.x) * 8;
    const float4 a = *(const float4*)(emb + i);
    const float4 b = *(const float4*)(emb + i + 4);
    ushort8 o;
    o[0] = f2bf(a.x); o[1] = f2bf(a.y); o[2] = f2bf(a.z); o[3] = f2bf(a.w);
    o[4] = f2bf(b.x); o[5] = f2bf(b.y); o[6] = f2bf(b.z); o[7] = f2bf(b.w);
    *(ushort8*)(embh + i) = o;
}

// ---------------------------------------------------------------------------
// Pass 2: fused gather + mean-pool + MLP, RB=2 batch rows per block
// (2048 blocks, 256 threads).
// Gather: bf16 row = 256 B = 16 slots x 16 B. g = t>>4 (16 position groups),
// d = t&15 (slot). 4-deep unroll -> 64 positions/round, indices prefetched
// from LDS before the vmcnt wait. Positions >= L use row 0 (all zeros,
// padding_idx=0). Accumulation in fp32.
// MLP: thread t computes hidden unit t for both rows -> each W1 element is
// read ONCE per block (268 MB total L2 traffic vs 537 MB at RB=1).
// ---------------------------------------------------------------------------
__global__ __launch_bounds__(256) void fused_kernel(
    const int* __restrict__ x,              // [B, S]
    const int* __restrict__ lens,           // [B]
    const unsigned short* __restrict__ embh,// [VOCAB, EMB_DIM] bf16
    const float* __restrict__ W1,           // [EMB_DIM, HIDDEN]
    const float* __restrict__ b1,           // [HIDDEN]
    const float* __restrict__ W2,           // [HIDDEN, NUM_CLASSES]
    const float* __restrict__ b2,           // [NUM_CLASSES]
    float* __restrict__ out)                // [B, NUM_CLASSES]
{
    __shared__ int   sidx[RB][256];              // 2 KB
    __shared__ float tmp[16][16][8];             // 8 KB (group, slot, dim-in-slot)
    __shared__ float P[RB][EMB_DIM];             // 1 KB
    __shared__ float H[RB][HIDDEN];              // 2 KB
    __shared__ float part[RB][4][NUM_CLASSES];   // 640 B

    const int t  = threadIdx.x;
    const int b0 = blockIdx.x * RB;

    int Ls[RB];
    #pragma unroll
    for (int r = 0; r < RB; ++r) {
        Ls[r] = lens[b0 + r];
        int v = 0;
        if (t < Ls[r]) v = x[(long)(b0 + r) * S + t];   // L <= S = 200 < 256
        sidx[r][t] = v;
    }
    __syncthreads();

    const int g = t >> 4;   // position group 0..15
    const int d = t & 15;   // 16B slot within the 256B bf16 row

    for (int r = 0; r < RB; ++r) {
        const int L = Ls[r];
        const int nIter = ((L + 63) & ~63) >> 6;   // 1..4, block-uniform

        float acc[4][8];
        #pragma unroll
        for (int j = 0; j < 4; ++j)
            #pragma unroll
            for (int f = 0; f < 8; ++f) acc[j][f] = 0.f;

        int cur[4], nxt[4];
        #pragma unroll
        for (int j = 0; j < 4; ++j) cur[j] = sidx[r][g + 16 * j];

        for (int it = 0; it < nIter; ++it) {
            uint4 v[4];
            #pragma unroll
            for (int j = 0; j < 4; ++j)
                v[j] = *(const uint4*)(embh + (long)cur[j] * EMB_DIM + d * 8);

            // prefetch next round's indices before the vmcnt wait
            if (it + 1 < nIter) {
                const int nb = (it + 1) << 6;
                #pragma unroll
                for (int j = 0; j < 4; ++j) nxt[j] = sidx[r][nb + g + 16 * j];
            }

            #pragma unroll
            for (int j = 0; j < 4; ++j) {
                const unsigned c0 = v[j].x, c1 = v[j].y, c2 = v[j].z, c3 = v[j].w;
                acc[j][0] += __uint_as_float(c0 << 16);
                acc[j][1] += __uint_as_float(c0 & 0xffff0000u);
                acc[j][2] += __uint_as_float(c1 << 16);
                acc[j][3] += __uint_as_float(c1 & 0xffff0000u);
                acc[j][4] += __uint_as_float(c2 << 16);
                acc[j][5] += __uint_as_float(c2 & 0xffff0000u);
                acc[j][6] += __uint_as_float(c3 << 16);
                acc[j][7] += __uint_as_float(c3 & 0xffff0000u);
            }
            #pragma unroll
            for (int j = 0; j < 4; ++j) cur[j] = nxt[j];
        }

        #pragma unroll
        for (int f = 0; f < 8; ++f)
            tmp[g][d][f] = acc[0][f] + acc[1][f] + acc[2][f] + acc[3][f];
        __syncthreads();

        if (t < EMB_DIM) {   // dim t = slot(t>>3)*8 + (t&7)
            float s = 0.f;
            #pragma unroll
            for (int gg = 0; gg < 16; ++gg) s += tmp[gg][t >> 3][t & 7];
            P[r][t] = s / (float)L;
        }
        __syncthreads();     // tmp reused by next row
    }

    // Layer 1: hidden unit t for both rows; W1 element read once per block.
    {
        float h0a = 0.f, h0b = 0.f, h1a = 0.f, h1b = 0.f;
        for (int k = 0; k < EMB_DIM; k += 2) {
            const float wa = W1[(k)     * HIDDEN + t];
            const float wb = W1[(k + 1) * HIDDEN + t];
            h0a += P[0][k] * wa;  h0b += P[0][k + 1] * wb;
            h1a += P[1][k] * wa;  h1b += P[1][k + 1] * wb;
        }
        const float bb = b1[t];
        H[0][t] = fmaxf(h0a + h0b + bb, 0.f);
        H[1][t] = fmaxf(h1a + h1b + bb, 0.f);
    }
    __syncthreads();

    // Layer 2: RB * 4 k-segments * 20 classes = 160 threads, 64-FMA chains.
    if (t < RB * 4 * NUM_CLASSES) {
        const int r  = t / (4 * NUM_CLASSES);
        const int u  = t - r * 4 * NUM_CLASSES;
        const int j  = u / NUM_CLASSES;
        const int c  = u - j * NUM_CLASSES;
        const int k0 = j * 64;
        float a = 0.f;
        for (int k = k0; k < k0 + 64; ++k)
            a += H[r][k] * W2[k * NUM_CLASSES + c];
        part[r][j][c] = a;
    }
    __syncthreads();

    if (t < RB * NUM_CLASSES) {
        const int r = t / NUM_CLASSES;
        const int c = t - r * NUM_CLASSES;
        const float a = b2[c] + part[r][0][c] + part[r][1][c]
                              + part[r][2][c] + part[r][3][c];
        out[(long)(b0 + r) * NUM_CLASSES + c] = a;
    }
}

extern "C" void kernel_launch(void* const* d_in, const int* in_sizes, int n_in,
                              void* d_out, int out_size, void* d_ws, size_t ws_size,
                              hipStream_t stream) {
    const int*   x    = (const int*)d_in[0];
    const int*   lens = (const int*)d_in[1];
    const float* emb  = (const float*)d_in[2];
    const float* W1   = (const float*)d_in[3];
    const float* b1   = (const float*)d_in[4];
    const float* W2   = (const float*)d_in[5];
    const float* b2   = (const float*)d_in[6];
    float*       out  = (float*)d_out;

    unsigned short* embh = (unsigned short*)d_ws;   // 25.6 MB bf16 table

    // VOCAB*EMB_DIM = 12.8M elems / 8 per thread / 256 per block = 6250 blocks
    convert_kernel<<<(VOCAB * EMB_DIM) / (8 * 256), 256, 0, stream>>>(emb, embh);
    fused_kernel<<<B / RB, 256, 0, stream>>>(x, lens, embh, W1, b1, W2, b2, out);
}